// Round 1
// baseline (441.064 us; speedup 1.0000x reference)
//
#include <hip/hip_runtime.h>
#include <hip/hip_bf16.h>
#include <math.h>

// Problem constants (fixed by reference)
#define BATCH 4096
#define LNUM  4
#define NEIGH 32
#define FEAT  256
#define EMB   128

// ---------------------------------------------------------------------------
// K1: gather + sum over neighbors.
// S[(b*L+l)*256 + f] = sum_j features[neighs[b,l,j], f]
// Grid: 4096 blocks x 256 threads. Wave w handles layer w; lane reads float4.
// Each wave: 32 x 1KB coalesced row loads (64 lanes x 16B).
// ---------------------------------------------------------------------------
__global__ __launch_bounds__(256) void k1_gather_sum(
    const int* __restrict__ neighs, const float* __restrict__ features,
    float* __restrict__ S) {
  int b = blockIdx.x;
  int l = threadIdx.x >> 6;   // wave index = layer
  int lane = threadIdx.x & 63;
  const int* nbr = neighs + ((size_t)b * LNUM + l) * NEIGH;
  int myn = (lane < NEIGH) ? nbr[lane] : 0;
  float4 acc = make_float4(0.f, 0.f, 0.f, 0.f);
#pragma unroll 8
  for (int j = 0; j < NEIGH; ++j) {
    int n = __shfl(myn, j, 64);
    float4 v = ((const float4*)(features + (size_t)n * FEAT))[lane];
    acc.x += v.x; acc.y += v.y; acc.z += v.z; acc.w += v.w;
  }
  ((float4*)S)[((size_t)b * LNUM + l) * (FEAT / 4) + lane] = acc;
}

// ---------------------------------------------------------------------------
// K2: H[(b*L+l)*128 + m] = sum_f S[(b*L+l)*256+f] * W[l*F*M + f*M + m]
// Grid: (4096/32, 4), block 128. Tile: 32 rows x 128 cols, K=256.
// S tile staged in LDS; thread (tx,ty) computes 8 rows x 4 cols.
// ---------------------------------------------------------------------------
__global__ __launch_bounds__(128) void k2_h(
    const float* __restrict__ S, const float* __restrict__ W,
    float* __restrict__ H) {
  __shared__ float sS[32 * FEAT];  // 32 KB
  int l = blockIdx.y;
  int b0 = blockIdx.x * 32;
  const float* Wl = W + (size_t)l * FEAT * EMB;
  // stage 32 rows of S (rows (b0+r, l))
  for (int i = threadIdx.x; i < 32 * (FEAT / 4); i += 128) {
    int r = i >> 6;  // / (FEAT/4)
    int c = i & 63;
    ((float4*)sS)[i] =
        ((const float4*)S)[((size_t)(b0 + r) * LNUM + l) * (FEAT / 4) + c];
  }
  __syncthreads();
  int tx = threadIdx.x & 31;   // column group: cols tx*4..tx*4+3
  int ty = threadIdx.x >> 5;   // row group: rows ty*8..ty*8+7
  float acc[8][4] = {};
#pragma unroll 4
  for (int k = 0; k < FEAT; ++k) {
    float4 w = ((const float4*)(Wl + (size_t)k * EMB))[tx];
#pragma unroll
    for (int r = 0; r < 8; ++r) {
      float s = sS[(ty * 8 + r) * FEAT + k];
      acc[r][0] += s * w.x; acc[r][1] += s * w.y;
      acc[r][2] += s * w.z; acc[r][3] += s * w.w;
    }
  }
#pragma unroll
  for (int r = 0; r < 8; ++r) {
    int b = b0 + ty * 8 + r;
    float4 o = make_float4(acc[r][0], acc[r][1], acc[r][2], acc[r][3]);
    ((float4*)H)[((size_t)b * LNUM + l) * (EMB / 4) + tx] = o;
  }
}

// ---------------------------------------------------------------------------
// K3: scores[row] = sum_c tanh( sum_k H[row,k]*Ws1[k,c] ) * Ws2[c]
// rows = b*4+l, 16384 rows. Grid 512, block 128. Tile 32 rows x 128 cols.
// ---------------------------------------------------------------------------
__global__ __launch_bounds__(128) void k3_scores(
    const float* __restrict__ H, const float* __restrict__ Ws1,
    const float* __restrict__ Ws2, float* __restrict__ scores) {
  __shared__ float sH[32 * EMB];  // 16 KB
  int r0 = blockIdx.x * 32;
  for (int i = threadIdx.x; i < 32 * (EMB / 4); i += 128) {
    ((float4*)sH)[i] = ((const float4*)H)[(size_t)r0 * (EMB / 4) + i];
  }
  __syncthreads();
  int tx = threadIdx.x & 31;
  int ty = threadIdx.x >> 5;
  float acc[8][4] = {};
#pragma unroll 4
  for (int k = 0; k < EMB; ++k) {
    float4 w = ((const float4*)(Ws1 + (size_t)k * EMB))[tx];
#pragma unroll
    for (int r = 0; r < 8; ++r) {
      float h = sH[(ty * 8 + r) * EMB + k];
      acc[r][0] += h * w.x; acc[r][1] += h * w.y;
      acc[r][2] += h * w.z; acc[r][3] += h * w.w;
    }
  }
  float4 w2 = ((const float4*)Ws2)[tx];
#pragma unroll
  for (int r = 0; r < 8; ++r) {
    float p = tanhf(acc[r][0]) * w2.x + tanhf(acc[r][1]) * w2.y +
              tanhf(acc[r][2]) * w2.z + tanhf(acc[r][3]) * w2.w;
    // reduce over tx: lanes with the same ty live in one 32-lane half
#pragma unroll
    for (int m = 1; m < 32; m <<= 1) p += __shfl_xor(p, m, 64);
    if (tx == 0) scores[r0 + ty * 8 + r] = p;
  }
}

// ---------------------------------------------------------------------------
// K4: softmax over L, agg = sum_l att*H, out = agg@Wt + layer_embs gather,
//     then L2-normalize each row. Grid 256 blocks x 256 threads, 16 b/block.
// ---------------------------------------------------------------------------
__global__ __launch_bounds__(256) void k4_out(
    const float* __restrict__ H, const float* __restrict__ scores,
    const float* __restrict__ Wt, const int* __restrict__ node_i,
    const int* __restrict__ layers, const float* __restrict__ layer_embs,
    float* __restrict__ out) {
  __shared__ float sAgg[16 * EMB];  // 8 KB
  __shared__ float sAtt[16 * LNUM];
  int b0 = blockIdx.x * 16;
  int tid = threadIdx.x;
  if (tid < 16 * LNUM) {
    int b = b0 + (tid >> 2);
    int l = tid & 3;
    float s0 = scores[b * 4 + 0], s1 = scores[b * 4 + 1];
    float s2 = scores[b * 4 + 2], s3 = scores[b * 4 + 3];
    float mx = fmaxf(fmaxf(s0, s1), fmaxf(s2, s3));
    float sum = expf(s0 - mx) + expf(s1 - mx) + expf(s2 - mx) + expf(s3 - mx);
    sAtt[tid] = expf(scores[b * 4 + l] - mx) / sum;
  }
  __syncthreads();
  for (int i = tid; i < 16 * EMB; i += 256) {
    int r = i >> 7;
    int m = i & 127;
    int b = b0 + r;
    float a = 0.f;
#pragma unroll
    for (int l = 0; l < LNUM; ++l)
      a += sAtt[r * 4 + l] * H[((size_t)b * LNUM + l) * EMB + m];
    sAgg[i] = a;
  }
  __syncthreads();
  int tx = tid & 31;   // cols tx*4..+3
  int ty = tid >> 5;   // rows ty*2..+1
  float acc[2][4] = {};
#pragma unroll 4
  for (int k = 0; k < EMB; ++k) {
    float4 w = ((const float4*)(Wt + (size_t)k * EMB))[tx];
#pragma unroll
    for (int r = 0; r < 2; ++r) {
      float a = sAgg[(ty * 2 + r) * EMB + k];
      acc[r][0] += a * w.x; acc[r][1] += a * w.y;
      acc[r][2] += a * w.z; acc[r][3] += a * w.w;
    }
  }
#pragma unroll
  for (int r = 0; r < 2; ++r) {
    int b = b0 + ty * 2 + r;
    int node = node_i[b];
    int lay = layers[b];
    float4 e =
        ((const float4*)(layer_embs + ((size_t)node * LNUM + lay) * EMB))[tx];
    acc[r][0] += e.x; acc[r][1] += e.y; acc[r][2] += e.z; acc[r][3] += e.w;
    float ss = acc[r][0] * acc[r][0] + acc[r][1] * acc[r][1] +
               acc[r][2] * acc[r][2] + acc[r][3] * acc[r][3];
#pragma unroll
    for (int m = 1; m < 32; m <<= 1) ss += __shfl_xor(ss, m, 64);
    float inv = 1.0f / fmaxf(sqrtf(ss), 1e-12f);
    float4 o = make_float4(acc[r][0] * inv, acc[r][1] * inv, acc[r][2] * inv,
                           acc[r][3] * inv);
    ((float4*)out)[(size_t)b * (EMB / 4) + tx] = o;
  }
}

extern "C" void kernel_launch(void* const* d_in, const int* in_sizes, int n_in,
                              void* d_out, int out_size, void* d_ws,
                              size_t ws_size, hipStream_t stream) {
  const int* layers = (const int*)d_in[0];
  const int* node_i = (const int*)d_in[1];
  const int* neighs = (const int*)d_in[2];
  const float* features = (const float*)d_in[3];
  const float* layer_embs = (const float*)d_in[4];
  const float* neigh_emb_trans = (const float*)d_in[5];
  const float* trans_weights = (const float*)d_in[6];
  const float* trans_weights_s1 = (const float*)d_in[7];
  const float* trans_weights_s2 = (const float*)d_in[8];
  float* out = (float*)d_out;

  // workspace layout (floats): S [16384*256] | H [16384*128] | scores [16384]
  float* S = (float*)d_ws;
  float* H = S + (size_t)BATCH * LNUM * FEAT;
  float* scores = H + (size_t)BATCH * LNUM * EMB;

  k1_gather_sum<<<dim3(BATCH), 256, 0, stream>>>(neighs, features, S);
  k2_h<<<dim3(BATCH / 32, LNUM), 128, 0, stream>>>(S, neigh_emb_trans, H);
  k3_scores<<<dim3(BATCH * LNUM / 32), 128, 0, stream>>>(
      H, trans_weights_s1, trans_weights_s2, scores);
  k4_out<<<dim3(BATCH / 16), 256, 0, stream>>>(H, scores, trans_weights,
                                               node_i, layers, layer_embs, out);
}